// Round 9
// baseline (615.741 us; speedup 1.0000x reference)
//
#include <hip/hip_runtime.h>

#define IN_DIM   512
#define OUT_DIM  256
#define N_MID    1280
#define BATCH    16384
#define NT       256
#define XPAD     520      // fallback kernel x stride

// R8-R15: 4-wave cooperative net7 (barrier per chunk). Best 185us.
// R15 ABLATION: scaffolding ~160us of 185, resolve ~25us -> stall-dominated,
//   cross-wave chunk pipeline (LDS handoff + barrier drain) is the wall.
// R16: 2 blocks/CU: occupancy 2x, time 185->207 (chain instances doubled).
// R17 (net9 v1): wave-independent phase 2 -- CRASHED: one-shot redistribution
//   wrote TPM*4096B (196KB) into the 64KB xa buffer. LDS OOB.
// R18 (this round): redistribution ELIMINATED. Phase 1 computes directly in
//   the target decomposition: wave w = rows [16w,16w+16) x ALL tiles
//   (a-frag = own row block only; B loaded per tile -- 4x redundant B-loads,
//   L2-resident, ~4us). acc[TPM] only (192/256 VGPR). ONE barrier total
//   (post-staging); phase 2 is barrier-free per-wave: stage -> resolve(16) ->
//   pack -> bridge(bfx) -> resolve(16) -> pack -> running-apply -> stores,
//   all same-wave LDS (compiler lgkm ordering). tri per-wave g->reg->LDS dbuf.

// ---- workspace layout (max geometry: ksteps=48, tpm=64, nch=32) ----
#define EW2_ELEMS ((size_t)48 * 64 * 64 * 8)               // bf16 elems
#define EW2_BYTES (EW2_ELEMS * 2)                          // 3,145,728
#define TRI_OFF   EW2_BYTES
#define TRI_BYTES ((size_t)32 * 1024 * 4)                  // 131,072
#define HDR_OFF   (TRI_OFF + TRI_BYTES)
#define CMAP_OFF  (HDR_OFF + 32)
#define OCOL_OFF  (CMAP_OFF + N_MID * 4)
#define BIASC_OFF (OCOL_OFF + N_MID * 4)
#define BFX_OFF   (BIASC_OFF + N_MID * 4)
#define BFX_BYTES ((size_t)32 * 64 * 8 * 2)                // 32,768
#define WS_NEED   (BFX_OFF + BFX_BYTES)

#define NEG_LOG2E (-1.44269504088896340736f)

typedef __attribute__((ext_vector_type(8))) short  bfrag;
typedef __attribute__((ext_vector_type(4))) float  ffrag;

__device__ __forceinline__ unsigned short f2bf(float f) {
    unsigned int u = __float_as_uint(f);
    u += 0x7FFFu + ((u >> 16) & 1u);       // RNE
    return (unsigned short)(u >> 16);
}

// raw HW exp2 (no OCML subnormal fixup -- R11 lesson)
__device__ __forceinline__ float fast_exp2(float x) {
#if __has_builtin(__builtin_amdgcn_exp2f)
    return __builtin_amdgcn_exp2f(x);
#else
    float r;
    asm("v_exp_f32 %0, %1" : "=v"(r) : "v"(x));
    return r;
#endif
}

// raw HW rcp (single instr)
__device__ __forceinline__ float fast_rcp(float x) {
#if __has_builtin(__builtin_amdgcn_rcpf)
    return __builtin_amdgcn_rcpf(x);
#else
    float r;
    asm("v_rcp_f32 %0, %1" : "=v"(r) : "v"(x));
    return r;
#endif
}

// packed f32x2 -> bf16x2 (RNE)
__device__ __forceinline__ unsigned int cvt_pk_bf16(float lo, float hi) {
    unsigned int r;
    asm("v_cvt_pk_bf16_f32 %0, %1, %2" : "=v"(r) : "v"(lo), "v"(hi));
    return r;
}

// ============================================================
// Setup A: compact existing columns (1 wave).
// hdr = {Mc, Mpad, unused, nch=Mpad/32, tpm=Mpad/16}
// ============================================================
__global__ void build_maps_kernel(const int* __restrict__ exist,
                                  const float* __restrict__ bias,
                                  int* __restrict__ hdr,
                                  int* __restrict__ cmap,
                                  int* __restrict__ ocol,
                                  float* __restrict__ biasc) {
    const int lane = threadIdx.x;   // 64
    int base = 0;
    for (int r = 0; r < N_MID / 64; ++r) {
        const int i = r * 64 + lane;
        const int e = exist[i];
        const unsigned long long m  = __ballot(e != 0);
        const unsigned long long lt = (lane == 0) ? 0ull : (~0ull >> (64 - lane));
        const int pos = base + __popcll(m & lt);
        if (e) {
            cmap[pos]  = i;
            ocol[pos]  = (i >= N_MID - OUT_DIM) ? (i - (N_MID - OUT_DIM)) : -1;
            biasc[pos] = bias[i];
        }
        base += __popcll(m);
    }
    for (int idx = base + lane; idx < N_MID; idx += 64) {
        cmap[idx] = 0; ocol[idx] = -1; biasc[idx] = 0.f;
    }
    if (lane == 0) {
        const int Mc = base;
        int Mpad;
        if (Mc <= 768) Mpad = 768;
        else if (Mc <= 1024) Mpad = 1024;
        else Mpad = (Mc + 127) & ~127;     // v1 fallback territory
        hdr[0] = Mc; hdr[1] = Mpad; hdr[2] = 0;
        hdr[3] = Mpad / 32; hdr[4] = Mpad / 16;
    }
}

// ============================================================
// Setup B (merged, ONE dispatch): all weights PRE-SCALED by -log2e.
//  blocks [0,768):   ew2 gather -> bf16 MFMA B-fragment-major.
//  blocks [768,896): tri = in-chunk triangle, fp32, scaled.
//  blocks [896,904): bfx = in-chunk lower->upper cross block, bf16 B-frags,
//    scaled, zero for k>=16.
// ============================================================
__global__ __launch_bounds__(NT)
void gather_all_kernel(const float* __restrict__ w, const int* __restrict__ conn,
                       const int* __restrict__ hdr, const int* __restrict__ cmap,
                       unsigned short* __restrict__ ew2, float* __restrict__ tri,
                       unsigned short* __restrict__ bfx) {
    const int Mc = hdr[0], nch = hdr[3], tpm = hdr[4];
    const int bx = blockIdx.x;
    if (bx < 768) {
        if (tpm > 64) return;                      // v1 fallback case
        const int tid  = bx * NT + threadIdx.x;
        const int lane = tid & 63;
        const int gl   = tid >> 6;
        const int gt   = gl % tpm;
        const int kstep = gl / tpm;
        if (kstep >= 16 + nch) return;
        const int c  = gt * 16 + (lane & 15);
        const int k0 = kstep * 32 + ((lane >> 4) << 3);
        unsigned short v[8];
#pragma unroll
        for (int jj = 0; jj < 8; ++jj) {
            const int s = k0 + jj;
            float val = 0.f;
            if (c < Mc) {
                const int cc = cmap[c];
                if (s < IN_DIM) {
                    const size_t o = (size_t)s * N_MID + cc;
                    val = w[o] * (float)conn[o] * NEG_LOG2E;
                } else {
                    const int s2 = s - IN_DIM;
                    if (s2 < Mc && s2 < c && (s2 >> 5) != (c >> 5)) {
                        const size_t o = (size_t)(IN_DIM + cmap[s2]) * N_MID + cc;
                        val = w[o] * (float)conn[o] * NEG_LOG2E;
                    }
                }
            }
            v[jj] = f2bf(val);
        }
        *(uint4*)&ew2[((size_t)(kstep * tpm + gt) * 64 + lane) * 8] = *(uint4*)v;
    } else if (bx < 896) {
        if (tpm > 64) return;
        const int idx = (bx - 768) * NT + threadIdx.x;   // < 32*1024
        const int j  = idx >> 10;
        if (j >= nch) return;
        const int sl = (idx >> 5) & 31;
        const int cl = idx & 31;
        const int s = j * 32 + sl, c = j * 32 + cl;
        float v = 0.f;
        if (sl < cl && c < Mc) {
            const size_t o = (size_t)(IN_DIM + cmap[s]) * N_MID + cmap[c];
            v = w[o] * (float)conn[o] * NEG_LOG2E;
        }
        tri[idx] = v;
    } else {
        if (tpm > 64) return;
        const int j = (bx - 896) * 4 + (threadIdx.x >> 6);
        if (j >= nch || j >= 32) return;
        const int lane = threadIdx.x & 63;
        const int cl = lane & 15, qq = lane >> 4;
        const int cg = 32 * j + 16 + cl;
        unsigned short v[8];
#pragma unroll
        for (int jj = 0; jj < 8; ++jj) {
            const int k = qq * 8 + jj;
            float val = 0.f;
            if (k < 16 && cg < Mc) {
                const size_t o = (size_t)(IN_DIM + cmap[32 * j + k]) * N_MID + cmap[cg];
                val = w[o] * (float)conn[o] * NEG_LOG2E;
            }
            v[jj] = f2bf(val);
        }
        *(uint4*)&bfx[((size_t)j * 64 + lane) * 8] = *(uint4*)v;
    }
}

// helper: static component select from float4 (constant-folded post-unroll)
__device__ __forceinline__ float f4c(const float4& v, int k) {
    return (k == 0) ? v.x : (k == 1) ? v.y : (k == 2) ? v.z : v.w;
}

// ============================================================
// Main kernel (net9): 256 blocks x 256 threads (4 waves), 64 rows/block.
// Wave w owns rows [16w,16w+16) x ALL tiles: acc[TPM] ffrags.
// Phase 1 computes directly in this decomposition (a-frag = own row block,
// B per tile; 4x redundant B-loads are L2-resident). ONE barrier (staging);
// phase 2 is fully wave-independent.
// ============================================================
template <int TPW>
__global__ __launch_bounds__(256)
__attribute__((amdgpu_waves_per_eu(1, 1)))
void net9_kernel(const float* __restrict__ x,
                 const unsigned short* __restrict__ ew2,
                 const float* __restrict__ tri_g,
                 const int* __restrict__ hdr,
                 const int* __restrict__ ocol,
                 const float* __restrict__ biasc,
                 const unsigned short* __restrict__ bfx,
                 float* __restrict__ out) {
    if (hdr[1] != TPW * 64) return;
    constexpr int TPM = TPW * 4;               // tiles (Mpad/16)
    const int Mc  = hdr[0];
    const int tpm = TPM;
    const int nch = TPW * 2;                   // Mpad/32

    __shared__ __align__(16) unsigned short xa[4096 * 8];      // 65,536 B
    __shared__ __align__(16) float trib_s[4][2][1024];         // 32,768 B (per-wave tri dbuf)
    __shared__ __align__(16) float stage_s[4][32 * 20];        // 10,240 B (per-wave [col][20])
    __shared__ __align__(16) unsigned short apack_s[4][512];   //  4,096 B (per-wave A-frag)
    __shared__ float bias_lds[1024];                           //  4,096 B
    __shared__ int   ocol_lds[1024];                           //  4,096 B
    // total ~120.8 KB -> 1 block/CU

    const int t = threadIdx.x, lane = t & 63, w = t >> 6;  // w in 0..3
    const int l15 = lane & 15, q = lane >> 4;
    const int r0 = blockIdx.x * 64;

    for (int i = t; i < TPW * 64; i += 256) {
        bias_lds[i] = biasc[i];
        ocol_lds[i] = ocol[i];
    }
    // ---- per-wave init: zero apack, stage tri chunk 0 ----
    {
        uint4 z; z.x = 0u; z.y = 0u; z.z = 0u; z.w = 0u;
        *(uint4*)&apack_s[w][lane * 8] = z;
#pragma unroll
        for (int u = 0; u < 4; ++u) {
            const float4 tv = *(const float4*)&tri_g[u * 256 + lane * 4];
            *(float4*)&trib_s[w][0][u * 256 + lane * 4] = tv;
        }
    }
    // ---- x -> bf16 A-fragment-contiguous: frag i = (kb*4+rr)*64 + lane2 ----
    for (int i = t; i < 4096; i += 256) {
        const int lane2 = i & 63, rrkb = i >> 6;
        const int rr = rrkb & 3, kb = rrkb >> 2;
        const int qq = lane2 >> 4, ll = lane2 & 15;
        const int row = rr * 16 + ll;
        const int k0 = kb * 32 + qq * 8;
        const float4 f0 = *(const float4*)&x[(size_t)(r0 + row) * IN_DIM + k0];
        const float4 f1 = *(const float4*)&x[(size_t)(r0 + row) * IN_DIM + k0 + 4];
        unsigned int uu[4] = {cvt_pk_bf16(f0.x, f0.y), cvt_pk_bf16(f0.z, f0.w),
                              cvt_pk_bf16(f1.x, f1.y), cvt_pk_bf16(f1.z, f1.w)};
        *(uint4*)&xa[(size_t)i * 8] = *(uint4*)uu;
    }
    __syncthreads();                           // the ONLY barrier

    // ---- phase 1: per-wave rows x all tiles ----
    ffrag acc[TPM];
#pragma unroll
    for (int tt = 0; tt < TPM; ++tt) acc[tt] = (ffrag)0.f;

#pragma unroll 1
    for (int kb = 0; kb < 16; ++kb) {
        const bfrag a = *(const bfrag*)&xa[((kb * 4 + w) * 64 + lane) * 8];
#pragma unroll
        for (int tt = 0; tt < TPM; ++tt) {
            if (tt * 16 < Mc) {
                const bfrag b = *(const bfrag*)&ew2[((size_t)(kb * tpm + tt) * 64 + lane) * 8];
                acc[tt] = __builtin_amdgcn_mfma_f32_16x16x32_bf16(a, b, acc[tt], 0, 0, 0);
            }
        }
    }

    // ---- phase 2: barrier-free per-wave chunk loop ----
    float* stg = stage_s[w];
    unsigned short* apk = apack_s[w];
    const int wrow0 = r0 + 16 * w;

#pragma unroll 1
    for (int j = 0; j < nch; ++j) {
        const int cbase = 32 * j;
        if (cbase >= Mc) break;                          // uniform

        // prefetch tri j+1 (global -> regs; LDS write at chunk end)
        const bool tok = (j + 1 < nch) && (32 * (j + 1) < Mc);
        float4 tpre[4];
        if (tok) {
#pragma unroll
            for (int u = 0; u < 4; ++u)
                tpre[u] = *(const float4*)&tri_g[(size_t)(j + 1) * 1024 + u * 256 + lane * 4];
        }
        const bfrag bc = *(const bfrag*)&bfx[((size_t)j * 64 + lane) * 8];

        // ---- stage lower tile 2j: [col][row], stride 20 ----
#pragma unroll
        for (int tt = 0; tt < TPM; ++tt)
            if (tt == 2 * j)
                *(ffrag*)&stg[l15 * 20 + 4 * q] = acc[tt];

        const float* trij = &trib_s[w][j & 1][0];
        float reg[32];
#pragma unroll
        for (int c = 0; c < 16; ++c) reg[c] = stg[c * 20 + l15];

        float4 tr[2][8];
#pragma unroll
        for (int u = 0; u < 4; ++u) tr[0][u] = *(const float4*)&trij[u * 4];

        // ---- resolve cols 0-15 (exp2 domain; lanes>=16 redundant) ----
#pragma unroll
        for (int c = 0; c < 16; ++c) {
            const int cb = c & 1;
            if (c < 15) {
#pragma unroll
                for (int u = (c + 2) >> 2; u < 4; ++u)
                    tr[cb ^ 1][u] = *(const float4*)&trij[(c + 1) * 32 + u * 4];
            }
            const float e  = fast_exp2(reg[c]);
            const float s  = fast_rcp(1.f + e);
            const float rs = s + bias_lds[cbase + c];
            reg[c] = rs;
#pragma unroll
            for (int k = c + 1; k < 16; ++k)
                reg[k] = fmaf(rs, f4c(tr[cb][k >> 2], k & 3), reg[k]);
        }
        // ---- pack lower rs -> apack[row][k 0..16) (lanes<16: row=lane) ----
        if (lane < 16) {
#pragma unroll
            for (int qA = 0; qA < 2; ++qA) {
                unsigned int u[4];
#pragma unroll
                for (int i = 0; i < 4; ++i)
                    u[i] = cvt_pk_bf16(reg[qA * 8 + 2 * i], reg[qA * 8 + 2 * i + 1]);
                *(uint4*)&apk[lane * 32 + qA * 8] = *(uint4*)u;
            }
        }
        // ---- bridge: lower -> upper tile (bc zero for k>=16; apack
        //      quarters 2,3 hold stale finite values x 0) ----
        {
            const bfrag aB = *(const bfrag*)&apk[l15 * 32 + q * 8];
#pragma unroll
            for (int tt = 0; tt < TPM; ++tt) {
                if (tt == 2 * j + 1) {
                    acc[tt] = __builtin_amdgcn_mfma_f32_16x16x32_bf16(aB, bc, acc[tt], 0, 0, 0);
                    *(ffrag*)&stg[(16 + l15) * 20 + 4 * q] = acc[tt];
                }
            }
        }
#pragma unroll
        for (int c = 16; c < 32; ++c) reg[c] = stg[c * 20 + l15];
#pragma unroll
        for (int u = 4; u < 8; ++u) tr[0][u] = *(const float4*)&trij[16 * 32 + u * 4];

        // ---- resolve cols 16-31 ----
#pragma unroll
        for (int c = 16; c < 32; ++c) {
            const int cb = c & 1;
            if (c < 31) {
#pragma unroll
                for (int u = (c + 2) >> 2; u < 8; ++u)
                    tr[cb ^ 1][u] = *(const float4*)&trij[(c + 1) * 32 + u * 4];
            }
            const float e  = fast_exp2(reg[c]);
            const float s  = fast_rcp(1.f + e);
            const float rs = s + bias_lds[cbase + c];
            reg[c] = rs;
#pragma unroll
            for (int k = c + 1; k < 32; ++k)
                reg[k] = fmaf(rs, f4c(tr[cb][k >> 2], k & 3), reg[k]);
        }
        // ---- pack upper rs -> apack[row][k 16..32) ----
        if (lane < 16) {
#pragma unroll
            for (int qA = 2; qA < 4; ++qA) {
                unsigned int u[4];
#pragma unroll
                for (int i = 0; i < 4; ++i)
                    u[i] = cvt_pk_bf16(reg[qA * 8 + 2 * i], reg[qA * 8 + 2 * i + 1]);
                *(uint4*)&apk[lane * 32 + qA * 8] = *(uint4*)u;
            }
        }
        // ---- running-apply res_j to all tiles t >= 2j+2 ----
        {
            const bfrag aF = *(const bfrag*)&apk[l15 * 32 + q * 8];
#pragma unroll
            for (int tt = 0; tt < TPM; ++tt) {
                if (tt >= 2 * j + 2 && tt * 16 < Mc) {
                    const bfrag b = *(const bfrag*)&ew2[((size_t)((16 + j) * tpm + tt) * 64 + lane) * 8];
                    acc[tt] = __builtin_amdgcn_mfma_f32_16x16x32_bf16(aF, b, acc[tt], 0, 0, 0);
                }
            }
        }
        // ---- out stores: lanes<16, row = wrow0 + lane ----
        if (lane < 16) {
#pragma unroll
            for (int c4 = 0; c4 < 8; ++c4) {
                const int oc0 = ocol_lds[cbase + c4 * 4];        // uniform
                const int oc3 = ocol_lds[cbase + c4 * 4 + 3];
                if (oc0 >= 0 && oc3 == oc0 + 3 && (oc0 & 3) == 0) {
                    const float4 v = make_float4(reg[c4 * 4], reg[c4 * 4 + 1],
                                                 reg[c4 * 4 + 2], reg[c4 * 4 + 3]);
                    *(float4*)&out[(size_t)(wrow0 + lane) * OUT_DIM + oc0] = v;
                } else {
#pragma unroll
                    for (int c = c4 * 4; c < c4 * 4 + 4; ++c) {
                        const int oc = ocol_lds[cbase + c];
                        if (oc >= 0)
                            out[(size_t)(wrow0 + lane) * OUT_DIM + oc] = reg[c];
                    }
                }
            }
        }
        // ---- write tri j+1 to the other per-wave buffer ----
        if (tok) {
#pragma unroll
            for (int u = 0; u < 4; ++u)
                *(float4*)&trib_s[w][(j + 1) & 1][u * 256 + lane * 4] = tpre[u];
        }
    }
}

// ============================================================
// Fallback (Mc > 1024 or tiny ws): round-1 monolithic fp32 kernel.
// ============================================================
__global__ __launch_bounds__(NT, 4)
void net_v1_kernel(const float* __restrict__ x,
                   const float* __restrict__ wsrc,
                   const int* __restrict__ conn,
                   const float* __restrict__ bias,
                   const int* __restrict__ exist,
                   const int* __restrict__ hdr,   // null = always run
                   float* __restrict__ out) {
    if (hdr && hdr[1] <= 1024) return;
    __shared__ float xs[16 * XPAD];
    __shared__ float res_s[2][16];
    float* bias_s  = xs;
    float* exist_s = xs + N_MID;
    const int t = threadIdx.x, rg = t & 3, cg = t >> 2;
    const int r0 = blockIdx.x * 16;
    const int c0 = cg * 20;
    {
        const float4* xg = (const float4*)(x + (size_t)r0 * IN_DIM);
        for (int idx = t; idx < 16 * IN_DIM / 4; idx += NT) {
            const int r = idx >> 7, jj = idx & 127;
            *(float4*)&xs[r * XPAD + jj * 4] = xg[idx];
        }
    }
    __syncthreads();
    float acc[4][20];
#pragma unroll
    for (int a = 0; a < 4; ++a)
#pragma unroll
        for (int k = 0; k < 20; ++k) acc[a][k] = 0.f;
    for (int j = 0; j < IN_DIM; ++j) {
        const size_t woff = (size_t)j * N_MID + c0;
        const float xv0 = xs[rg * XPAD + j];
        const float xv1 = xs[(rg + 4) * XPAD + j];
        const float xv2 = xs[(rg + 8) * XPAD + j];
        const float xv3 = xs[(rg + 12) * XPAD + j];
#pragma unroll
        for (int qq = 0; qq < 5; ++qq) {
            float4 w4 = *(const float4*)(wsrc + woff + qq * 4);
            const int4 c4 = *(const int4*)(conn + woff + qq * 4);
            w4.x *= (float)c4.x; w4.y *= (float)c4.y;
            w4.z *= (float)c4.z; w4.w *= (float)c4.w;
            const float wq[4] = {w4.x, w4.y, w4.z, w4.w};
#pragma unroll
            for (int u = 0; u < 4; ++u) {
                const int k = qq * 4 + u;
                acc[0][k] = fmaf(xv0, wq[u], acc[0][k]);
                acc[1][k] = fmaf(xv1, wq[u], acc[1][k]);
                acc[2][k] = fmaf(xv2, wq[u], acc[2][k]);
                acc[3][k] = fmaf(xv3, wq[u], acc[3][k]);
            }
        }
    }
    __syncthreads();
    for (int idx = t; idx < N_MID; idx += NT) {
        bias_s[idx]  = bias[idx];
        exist_s[idx] = (float)exist[idx];
    }
    __syncthreads();
    int p = 0;
    for (int bb = 0; bb < 64; ++bb) {
#pragma unroll
        for (int kk = 0; kk < 20; ++kk) {
            const int i = bb * 20 + kk;
            const float e = exist_s[i];
            if (e != 0.f) {
                if (cg == bb) {
                    const float bv = bias_s[i];
#pragma unroll
                    for (int a = 0; a < 4; ++a) {
                        const float v = acc[a][kk];
                        const float s = __fdividef(1.f, 1.f + __expf(-v));
                        const float res = (s + bv) * e;
                        res_s[p][rg + 4 * a] = res;
                        if (i >= N_MID - OUT_DIM)
                            out[(size_t)(r0 + rg + 4 * a) * OUT_DIM + (i - (N_MID - OUT_DIM))] = res;
                    }
                }
                __syncthreads();
                const float rv0 = res_s[p][rg];
                const float rv1 = res_s[p][rg + 4];
                const float rv2 = res_s[p][rg + 8];
                const float rv3 = res_s[p][rg + 12];
                const size_t woff = (size_t)(IN_DIM + i) * N_MID + c0;
                if (cg > bb) {
#pragma unroll
                    for (int qq = 0; qq < 5; ++qq) {
                        float4 w4 = *(const float4*)(wsrc + woff + qq * 4);
                        const int4 c4 = *(const int4*)(conn + woff + qq * 4);
                        w4.x *= (float)c4.x; w4.y *= (float)c4.y;
                        w4.z *= (float)c4.z; w4.w *= (float)c4.w;
                        const float wq[4] = {w4.x, w4.y, w4.z, w4.w};
#pragma unroll
                        for (int u = 0; u < 4; ++u) {
                            const int k = qq * 4 + u;
                            acc[0][k] = fmaf(rv0, wq[u], acc[0][k]);
                            acc[1][k] = fmaf(rv1, wq[u], acc[1][k]);
                            acc[2][k] = fmaf(rv2, wq[u], acc[2][k]);
                            acc[3][k] = fmaf(rv3, wq[u], acc[3][k]);
                        }
                    }
                } else if (cg == bb) {
#pragma unroll
                    for (int k = kk + 1; k < 20; ++k) {
                        float ww = wsrc[woff + k] * (float)conn[woff + k];
                        acc[0][k] = fmaf(rv0, ww, acc[0][k]);
                        acc[1][k] = fmaf(rv1, ww, acc[1][k]);
                        acc[2][k] = fmaf(rv2, ww, acc[2][k]);
                        acc[3][k] = fmaf(rv3, ww, acc[3][k]);
                    }
                }
                p ^= 1;
            }
        }
    }
}

extern "C" void kernel_launch(void* const* d_in, const int* in_sizes, int n_in,
                              void* d_out, int out_size, void* d_ws, size_t ws_size,
                              hipStream_t stream) {
    const float* x      = (const float*)d_in[0];
    const float* weight = (const float*)d_in[1];
    const float* bias   = (const float*)d_in[2];
    const int*   conn   = (const int*)d_in[3];
    const int*   exist  = (const int*)d_in[4];
    float*       out    = (float*)d_out;

    if (ws_size >= WS_NEED) {
        char* ws = (char*)d_ws;
        unsigned short* ew2  = (unsigned short*)ws;
        float*          tri  = (float*)(ws + TRI_OFF);
        int*            hdr  = (int*)(ws + HDR_OFF);
        int*            cmap = (int*)(ws + CMAP_OFF);
        int*            ocolp= (int*)(ws + OCOL_OFF);
        float*          bsc  = (float*)(ws + BIASC_OFF);
        unsigned short* bfx  = (unsigned short*)(ws + BFX_OFF);

        build_maps_kernel<<<1, 64, 0, stream>>>(exist, bias, hdr, cmap, ocolp, bsc);
        gather_all_kernel<<<904, NT, 0, stream>>>(weight, conn, hdr, cmap, ew2, tri, bfx);
        net9_kernel<12><<<BATCH / 64, 256, 0, stream>>>(x, ew2, tri, hdr, ocolp, bsc, bfx, out);
        net9_kernel<16><<<BATCH / 64, 256, 0, stream>>>(x, ew2, tri, hdr, ocolp, bsc, bfx, out);
        net_v1_kernel<<<BATCH / 16, NT, 0, stream>>>(x, weight, conn, bias, exist, hdr, out);
    } else {
        net_v1_kernel<<<BATCH / 16, NT, 0, stream>>>(x, weight, conn, bias, exist, nullptr, out);
    }
}

// Round 10
// 338.790 us; speedup vs baseline: 1.8175x; 1.8175x over previous
//
#include <hip/hip_runtime.h>

#define IN_DIM   512
#define OUT_DIM  256
#define N_MID    1280
#define BATCH    16384
#define NT       256
#define XPAD     520      // fallback kernel x stride

// R8-R15: 4-wave cooperative net7 (barrier/chunk). 185us. R15 ablation:
//   scaffolding ~160us of 185 -> cross-wave chunk pipeline is the wall.
// R16: 2 blocks/CU: occupancy 2x, time worse (chain instances doubled).
// R18 (net9): wave-independent phase 2, running-apply. PASSED but 528us:
//   (a) acc[48]=192 regs spilled (VGPR=148), (b) apack [row][k] layout =
//   8-way LDS bank conflicts (4.2M). Math validated.
// R19 (net10): same wave-independent architecture, fixed resources:
//   - PANEL form: tile-pair acc computed fresh at its chunk = input-GEMM
//     (x A-frags in 64 REGS, no LDS) + pipelined gather over hist of
//     resolved chunks (bf16 A-frags in per-wave LDS). acc live-set = 8 regs.
//   - hist frag-contiguous layout: b128 writes/reads fully conflict-free.
//   - ONE barrier total; waves fully independent in phase 2.
//   TPW=16 (rare; Mc<=768 expected) uses the verified net7 4-wave kernel.

// ---- workspace layout (max geometry: ksteps=48, tpm=64, nch=32) ----
#define EW2_ELEMS ((size_t)48 * 64 * 64 * 8)               // bf16 elems
#define EW2_BYTES (EW2_ELEMS * 2)                          // 3,145,728
#define TRI_OFF   EW2_BYTES
#define TRI_BYTES ((size_t)32 * 1024 * 4)                  // 131,072
#define HDR_OFF   (TRI_OFF + TRI_BYTES)
#define CMAP_OFF  (HDR_OFF + 32)
#define OCOL_OFF  (CMAP_OFF + N_MID * 4)
#define BIASC_OFF (OCOL_OFF + N_MID * 4)
#define BFX_OFF   (BIASC_OFF + N_MID * 4)
#define BFX_BYTES ((size_t)32 * 64 * 8 * 2)                // 32,768
#define WS_NEED   (BFX_OFF + BFX_BYTES)

#define NEG_LOG2E (-1.44269504088896340736f)

typedef __attribute__((ext_vector_type(8))) short  bfrag;
typedef __attribute__((ext_vector_type(4))) float  ffrag;

__device__ __forceinline__ unsigned short f2bf(float f) {
    unsigned int u = __float_as_uint(f);
    u += 0x7FFFu + ((u >> 16) & 1u);       // RNE
    return (unsigned short)(u >> 16);
}

// raw HW exp2 (no OCML subnormal fixup -- R11 lesson)
__device__ __forceinline__ float fast_exp2(float x) {
#if __has_builtin(__builtin_amdgcn_exp2f)
    return __builtin_amdgcn_exp2f(x);
#else
    float r;
    asm("v_exp_f32 %0, %1" : "=v"(r) : "v"(x));
    return r;
#endif
}

// raw HW rcp (single instr)
__device__ __forceinline__ float fast_rcp(float x) {
#if __has_builtin(__builtin_amdgcn_rcpf)
    return __builtin_amdgcn_rcpf(x);
#else
    float r;
    asm("v_rcp_f32 %0, %1" : "=v"(r) : "v"(x));
    return r;
#endif
}

// packed f32x2 -> bf16x2 (RNE)
__device__ __forceinline__ unsigned int cvt_pk_bf16(float lo, float hi) {
    unsigned int r;
    asm("v_cvt_pk_bf16_f32 %0, %1, %2" : "=v"(r) : "v"(lo), "v"(hi));
    return r;
}

// ============================================================
// Setup A: compact existing columns (1 wave).
// hdr = {Mc, Mpad, unused, nch=Mpad/32, tpm=Mpad/16}
// ============================================================
__global__ void build_maps_kernel(const int* __restrict__ exist,
                                  const float* __restrict__ bias,
                                  int* __restrict__ hdr,
                                  int* __restrict__ cmap,
                                  int* __restrict__ ocol,
                                  float* __restrict__ biasc) {
    const int lane = threadIdx.x;   // 64
    int base = 0;
    for (int r = 0; r < N_MID / 64; ++r) {
        const int i = r * 64 + lane;
        const int e = exist[i];
        const unsigned long long m  = __ballot(e != 0);
        const unsigned long long lt = (lane == 0) ? 0ull : (~0ull >> (64 - lane));
        const int pos = base + __popcll(m & lt);
        if (e) {
            cmap[pos]  = i;
            ocol[pos]  = (i >= N_MID - OUT_DIM) ? (i - (N_MID - OUT_DIM)) : -1;
            biasc[pos] = bias[i];
        }
        base += __popcll(m);
    }
    for (int idx = base + lane; idx < N_MID; idx += 64) {
        cmap[idx] = 0; ocol[idx] = -1; biasc[idx] = 0.f;
    }
    if (lane == 0) {
        const int Mc = base;
        int Mpad;
        if (Mc <= 768) Mpad = 768;
        else if (Mc <= 1024) Mpad = 1024;
        else Mpad = (Mc + 127) & ~127;     // v1 fallback territory
        hdr[0] = Mc; hdr[1] = Mpad; hdr[2] = 0;
        hdr[3] = Mpad / 32; hdr[4] = Mpad / 16;
    }
}

// ============================================================
// Setup B (merged, ONE dispatch): all weights PRE-SCALED by -log2e.
//  blocks [0,768):   ew2 gather -> bf16 MFMA B-fragment-major.
//  blocks [768,896): tri = in-chunk triangle, fp32, scaled.
//  blocks [896,904): bfx = in-chunk lower->upper cross block, bf16 B-frags,
//    scaled, zero for k>=16.
// ============================================================
__global__ __launch_bounds__(NT)
void gather_all_kernel(const float* __restrict__ w, const int* __restrict__ conn,
                       const int* __restrict__ hdr, const int* __restrict__ cmap,
                       unsigned short* __restrict__ ew2, float* __restrict__ tri,
                       unsigned short* __restrict__ bfx) {
    const int Mc = hdr[0], nch = hdr[3], tpm = hdr[4];
    const int bx = blockIdx.x;
    if (bx < 768) {
        if (tpm > 64) return;                      // v1 fallback case
        const int tid  = bx * NT + threadIdx.x;
        const int lane = tid & 63;
        const int gl   = tid >> 6;
        const int gt   = gl % tpm;
        const int kstep = gl / tpm;
        if (kstep >= 16 + nch) return;
        const int c  = gt * 16 + (lane & 15);
        const int k0 = kstep * 32 + ((lane >> 4) << 3);
        unsigned short v[8];
#pragma unroll
        for (int jj = 0; jj < 8; ++jj) {
            const int s = k0 + jj;
            float val = 0.f;
            if (c < Mc) {
                const int cc = cmap[c];
                if (s < IN_DIM) {
                    const size_t o = (size_t)s * N_MID + cc;
                    val = w[o] * (float)conn[o] * NEG_LOG2E;
                } else {
                    const int s2 = s - IN_DIM;
                    if (s2 < Mc && s2 < c && (s2 >> 5) != (c >> 5)) {
                        const size_t o = (size_t)(IN_DIM + cmap[s2]) * N_MID + cc;
                        val = w[o] * (float)conn[o] * NEG_LOG2E;
                    }
                }
            }
            v[jj] = f2bf(val);
        }
        *(uint4*)&ew2[((size_t)(kstep * tpm + gt) * 64 + lane) * 8] = *(uint4*)v;
    } else if (bx < 896) {
        if (tpm > 64) return;
        const int idx = (bx - 768) * NT + threadIdx.x;   // < 32*1024
        const int j  = idx >> 10;
        if (j >= nch) return;
        const int sl = (idx >> 5) & 31;
        const int cl = idx & 31;
        const int s = j * 32 + sl, c = j * 32 + cl;
        float v = 0.f;
        if (sl < cl && c < Mc) {
            const size_t o = (size_t)(IN_DIM + cmap[s]) * N_MID + cmap[c];
            v = w[o] * (float)conn[o] * NEG_LOG2E;
        }
        tri[idx] = v;
    } else {
        if (tpm > 64) return;
        const int j = (bx - 896) * 4 + (threadIdx.x >> 6);
        if (j >= nch || j >= 32) return;
        const int lane = threadIdx.x & 63;
        const int cl = lane & 15, qq = lane >> 4;
        const int cg = 32 * j + 16 + cl;
        unsigned short v[8];
#pragma unroll
        for (int jj = 0; jj < 8; ++jj) {
            const int k = qq * 8 + jj;
            float val = 0.f;
            if (k < 16 && cg < Mc) {
                const size_t o = (size_t)(IN_DIM + cmap[32 * j + k]) * N_MID + cmap[cg];
                val = w[o] * (float)conn[o] * NEG_LOG2E;
            }
            v[jj] = f2bf(val);
        }
        *(uint4*)&bfx[((size_t)j * 64 + lane) * 8] = *(uint4*)v;
    }
}

// helper: static component select from float4 (constant-folded post-unroll)
__device__ __forceinline__ float f4c(const float4& v, int k) {
    return (k == 0) ? v.x : (k == 1) ? v.y : (k == 2) ? v.z : v.w;
}

// ============================================================
// Main kernel (net10, TPW=12 only): 256 blocks x 256 threads (4 waves).
// Wave w owns rows [16w,16w+16); fully independent after one barrier.
// PANEL form per chunk j: acc pair = input-GEMM (xf regs) + pipelined
// hist applies (bf16 A-frags, frag-contiguous per-wave LDS, conflict-free)
// -> stage -> resolve lower -> pack -> bridge -> resolve upper -> pack ->
// out stores -> tri dbuf advance. Zero barriers in the loop.
// ============================================================
template <int TPW>
__global__ __launch_bounds__(256)
__attribute__((amdgpu_waves_per_eu(1, 1)))
void net10_kernel(const float* __restrict__ x,
                  const unsigned short* __restrict__ ew2,
                  const float* __restrict__ tri_g,
                  const int* __restrict__ hdr,
                  const int* __restrict__ ocol,
                  const float* __restrict__ biasc,
                  const unsigned short* __restrict__ bfx,
                  float* __restrict__ out) {
    if (hdr[1] != TPW * 64) return;
    constexpr int TPM = TPW * 4;       // 48 tiles
    constexpr int NCH = TPW * 2;       // 24 chunks
    const int Mc = hdr[0];

    __shared__ __align__(16) unsigned short hist_s[4][NCH * 512]; // 98,304 B
    __shared__ __align__(16) float trib_s[4][2][1024];            // 32,768 B
    __shared__ __align__(16) float stage_s[4][32 * 20];           // 10,240 B
    __shared__ float bias_lds[TPW * 64];                          //  3,072 B
    __shared__ int   ocol_lds[TPW * 64];                          //  3,072 B
    // total ~147.5 KB -> 1 block/CU

    const int t = threadIdx.x, lane = t & 63, w = t >> 6;  // w in 0..3
    const int l15 = lane & 15, q = lane >> 4;
    const int r0 = blockIdx.x * 64;
    const int wrow0 = r0 + 16 * w;

    for (int i = t; i < TPW * 64; i += 256) {
        bias_lds[i] = biasc[i];
        ocol_lds[i] = ocol[i];
    }
    // ---- per-wave init: zero hist, stage tri chunk 0 ----
    {
        uint4 z; z.x = 0u; z.y = 0u; z.z = 0u; z.w = 0u;
        uint4* h4 = (uint4*)hist_s[w];
        for (int i = lane; i < NCH * 64; i += 64) h4[i] = z;
#pragma unroll
        for (int u = 0; u < 4; ++u)
            *(float4*)&trib_s[w][0][u * 256 + lane * 4] =
                *(const float4*)&tri_g[u * 256 + lane * 4];
    }
    // ---- x A-frags -> registers (wave's 16 rows; no LDS round-trip) ----
    bfrag xf[16];
#pragma unroll
    for (int kb = 0; kb < 16; ++kb) {
        const float4 f0 = *(const float4*)&x[(size_t)(wrow0 + l15) * IN_DIM + kb * 32 + q * 8];
        const float4 f1 = *(const float4*)&x[(size_t)(wrow0 + l15) * IN_DIM + kb * 32 + q * 8 + 4];
        unsigned int uu[4] = {cvt_pk_bf16(f0.x, f0.y), cvt_pk_bf16(f0.z, f0.w),
                              cvt_pk_bf16(f1.x, f1.y), cvt_pk_bf16(f1.z, f1.w)};
        xf[kb] = *(const bfrag*)uu;
    }
    __syncthreads();                           // the ONLY barrier (bias/ocol)

    unsigned short* hist = hist_s[w];
    float* stg = stage_s[w];

#pragma unroll 1
    for (int j = 0; j < NCH; ++j) {
        const int cbase = 32 * j;
        if (cbase >= Mc) break;                          // uniform
        const int t0 = 2 * j, t1 = 2 * j + 1;

        // tri j+1 prefetch (global -> regs; LDS write at chunk end)
        const bool tok = (j + 1 < NCH) && (32 * (j + 1) < Mc);
        float4 tpre[4];
        if (tok) {
#pragma unroll
            for (int u = 0; u < 4; ++u)
                tpre[u] = *(const float4*)&tri_g[(size_t)(j + 1) * 1024 + u * 256 + lane * 4];
        }
        const bfrag bc = *(const bfrag*)&bfx[((size_t)j * 64 + lane) * 8];

        // ---- fresh acc pair: input GEMM (xf static, 32 indep MFMAs) ----
        ffrag acc0 = (ffrag)0.f, acc1 = (ffrag)0.f;
#pragma unroll
        for (int kb = 0; kb < 16; ++kb) {
            const bfrag b0 = *(const bfrag*)&ew2[((size_t)(kb * TPM + t0) * 64 + lane) * 8];
            const bfrag b1 = *(const bfrag*)&ew2[((size_t)(kb * TPM + t1) * 64 + lane) * 8];
            acc0 = __builtin_amdgcn_mfma_f32_16x16x32_bf16(xf[kb], b0, acc0, 0, 0, 0);
            acc1 = __builtin_amdgcn_mfma_f32_16x16x32_bf16(xf[kb], b1, acc1, 0, 0, 0);
        }
        // ---- hist applies p = 0..j-1, 2-deep pipelined ----
        {
            bfrag af = {}, b0 = {}, b1 = {};
            if (j > 0) {
                af = *(const bfrag*)&hist[lane * 8];
                b0 = *(const bfrag*)&ew2[((size_t)(16 * TPM + t0) * 64 + lane) * 8];
                b1 = *(const bfrag*)&ew2[((size_t)(16 * TPM + t1) * 64 + lane) * 8];
            }
#pragma unroll 2
            for (int p = 0; p < j; ++p) {
                bfrag afn = af, bn0 = b0, bn1 = b1;
                if (p + 1 < j) {
                    afn = *(const bfrag*)&hist[(size_t)(p + 1) * 512 + lane * 8];
                    bn0 = *(const bfrag*)&ew2[((size_t)((17 + p) * TPM + t0) * 64 + lane) * 8];
                    bn1 = *(const bfrag*)&ew2[((size_t)((17 + p) * TPM + t1) * 64 + lane) * 8];
                }
                acc0 = __builtin_amdgcn_mfma_f32_16x16x32_bf16(af, b0, acc0, 0, 0, 0);
                acc1 = __builtin_amdgcn_mfma_f32_16x16x32_bf16(af, b1, acc1, 0, 0, 0);
                af = afn; b0 = bn0; b1 = bn1;
            }
        }

        // ---- stage lower tile: [col][row], stride 20 (2-way, free) ----
        *(ffrag*)&stg[l15 * 20 + 4 * q] = acc0;

        const float* trij = &trib_s[w][j & 1][0];
        float reg[32];
#pragma unroll
        for (int c = 0; c < 16; ++c) reg[c] = stg[c * 20 + l15];

        float4 tr[2][8];
#pragma unroll
        for (int u = 0; u < 4; ++u) tr[0][u] = *(const float4*)&trij[u * 4];

        // ---- resolve cols 0-15 (exp2 domain; lanes>=16 redundant) ----
#pragma unroll
        for (int c = 0; c < 16; ++c) {
            const int cb = c & 1;
            if (c < 15) {
#pragma unroll
                for (int u = (c + 2) >> 2; u < 4; ++u)
                    tr[cb ^ 1][u] = *(const float4*)&trij[(c + 1) * 32 + u * 4];
            }
            const float e  = fast_exp2(reg[c]);
            const float s  = fast_rcp(1.f + e);
            const float rs = s + bias_lds[cbase + c];
            reg[c] = rs;
#pragma unroll
            for (int k = c + 1; k < 16; ++k)
                reg[k] = fmaf(rs, f4c(tr[cb][k >> 2], k & 3), reg[k]);
        }
        // ---- pack lower -> hist[j], FRAG-CONTIGUOUS (conflict-free) ----
        unsigned short* hj = &hist[(size_t)j * 512];
        if (lane < 16) {
#pragma unroll
            for (int qA = 0; qA < 2; ++qA) {
                unsigned int u[4];
#pragma unroll
                for (int i = 0; i < 4; ++i)
                    u[i] = cvt_pk_bf16(reg[qA * 8 + 2 * i], reg[qA * 8 + 2 * i + 1]);
                *(uint4*)&hj[(size_t)(qA * 16 + lane) * 8] = *(uint4*)u;
            }
        }
        // ---- bridge: lower -> upper tile (bc zero k>=16; hj q2,3 zeroed) ----
        {
            const bfrag aB = *(const bfrag*)&hj[lane * 8];
            acc1 = __builtin_amdgcn_mfma_f32_16x16x32_bf16(aB, bc, acc1, 0, 0, 0);
            *(ffrag*)&stg[(16 + l15) * 20 + 4 * q] = acc1;
        }
#pragma unroll
        for (int c = 16; c < 32; ++c) reg[c] = stg[c * 20 + l15];
#pragma unroll
        for (int u = 4; u < 8; ++u) tr[0][u] = *(const float4*)&trij[16 * 32 + u * 4];

        // ---- resolve cols 16-31 ----
#pragma unroll
        for (int c = 16; c < 32; ++c) {
            const int cb = c & 1;
            if (c < 31) {
#pragma unroll
                for (int u = (c + 2) >> 2; u < 8; ++u)
                    tr[cb ^ 1][u] = *(const float4*)&trij[(c + 1) * 32 + u * 4];
            }
            const float e  = fast_exp2(reg[c]);
            const float s  = fast_rcp(1.f + e);
            const float rs = s + bias_lds[cbase + c];
            reg[c] = rs;
#pragma unroll
            for (int k = c + 1; k < 32; ++k)
                reg[k] = fmaf(rs, f4c(tr[cb][k >> 2], k & 3), reg[k]);
        }
        // ---- pack upper + out stores (lanes<16, row = wrow0+lane) ----
        if (lane < 16) {
#pragma unroll
            for (int qA = 2; qA < 4; ++qA) {
                unsigned int u[4];
#pragma unroll
                for (int i = 0; i < 4; ++i)
                    u[i] = cvt_pk_bf16(reg[qA * 8 + 2 * i], reg[qA * 8 + 2 * i + 1]);
                *(uint4*)&hj[(size_t)(qA * 16 + lane) * 8] = *(uint4*)u;
            }
#pragma unroll
            for (int c4 = 0; c4 < 8; ++c4) {
                const int oc0 = ocol_lds[cbase + c4 * 4];        // uniform
                const int oc3 = ocol_lds[cbase + c4 * 4 + 3];
                if (oc0 >= 0 && oc3 == oc0 + 3 && (oc0 & 3) == 0) {
                    const float4 v = make_float4(reg[c4 * 4], reg[c4 * 4 + 1],
                                                 reg[c4 * 4 + 2], reg[c4 * 4 + 3]);
                    *(float4*)&out[(size_t)(wrow0 + lane) * OUT_DIM + oc0] = v;
                } else {
#pragma unroll
                    for (int c = c4 * 4; c < c4 * 4 + 4; ++c) {
                        const int oc = ocol_lds[cbase + c];
                        if (oc >= 0)
                            out[(size_t)(wrow0 + lane) * OUT_DIM + oc] = reg[c];
                    }
                }
            }
        }
        // ---- advance tri dbuf ----
        if (tok) {
#pragma unroll
            for (int u = 0; u < 4; ++u)
                *(float4*)&trib_s[w][(j + 1) & 1][u * 256 + lane * 4] = tpre[u];
        }
    }
}

// ============================================================
// net7 (R15-verified, 185us): 4-wave cooperative, used for Mpad=1024 only.
// ============================================================
template <int TPW>
__global__ __launch_bounds__(256)
__attribute__((amdgpu_waves_per_eu(1, 1)))
void net7_kernel(const float* __restrict__ x,
                 const unsigned short* __restrict__ ew2,
                 const float* __restrict__ tri_g,
                 const int* __restrict__ hdr,
                 const int* __restrict__ ocol,
                 const float* __restrict__ biasc,
                 const unsigned short* __restrict__ bfx,
                 float* __restrict__ out) {
    if (hdr[1] != TPW * 64) return;
    const int Mc  = hdr[0];
    const int tpm = TPW * 4;
    const int nch = TPW * 2;

    __shared__ __align__(16) unsigned short xa[4096 * 8];
    __shared__ __align__(16) float stage2[32 * 68];
    __shared__ __align__(16) unsigned short res2[2][2048];
    __shared__ __align__(16) float tri_lds[2][1024];
    __shared__ float bias_lds[1024];
    __shared__ int   ocol_lds[1024];

    const int t = threadIdx.x, lane = t & 63, w = t >> 6;
    const int l15 = lane & 15, q = lane >> 4;
    const int r0 = blockIdx.x * 64;
    const int g0 = w * TPW;

    for (int i = t; i < TPW * 64; i += 256) {
        bias_lds[i] = biasc[i];
        ocol_lds[i] = ocol[i];
    }
    {
        uint4 z; z.x = 0u; z.y = 0u; z.z = 0u; z.w = 0u;
        uint4* r2 = (uint4*)res2;
        for (int i = t; i < 512; i += 256) r2[i] = z;
    }
    if (w == 3) {
        const float4* src = (const float4*)tri_g;
#pragma unroll
        for (int u = 0; u < 4; ++u)
            *(float4*)&tri_lds[0][(lane + 64 * u) * 4] = src[lane + 64 * u];
    }
    for (int i = t; i < 4096; i += 256) {
        const int lane2 = i & 63, rrkb = i >> 6;
        const int rr = rrkb & 3, kb = rrkb >> 2;
        const int qq = lane2 >> 4, ll = lane2 & 15;
        const int row = rr * 16 + ll;
        const int k0 = kb * 32 + qq * 8;
        const float4 f0 = *(const float4*)&x[(size_t)(r0 + row) * IN_DIM + k0];
        const float4 f1 = *(const float4*)&x[(size_t)(r0 + row) * IN_DIM + k0 + 4];
        unsigned int uu[4] = {cvt_pk_bf16(f0.x, f0.y), cvt_pk_bf16(f0.z, f0.w),
                              cvt_pk_bf16(f1.x, f1.y), cvt_pk_bf16(f1.z, f1.w)};
        *(uint4*)&xa[(size_t)i * 8] = *(uint4*)uu;
    }
    __syncthreads();

    ffrag acc[TPW][4];
#pragma unroll
    for (int tt = 0; tt < TPW; ++tt)
#pragma unroll
        for (int rr = 0; rr < 4; ++rr) acc[tt][rr] = (ffrag)0.f;

#pragma unroll 1
    for (int kb = 0; kb < 16; ++kb) {
        bfrag a[4];
#pragma unroll
        for (int rr = 0; rr < 4; ++rr)
            a[rr] = *(const bfrag*)&xa[((kb * 4 + rr) * 64 + lane) * 8];
#pragma unroll
        for (int tt = 0; tt < TPW; ++tt) {
            if ((g0 + tt) * 16 < Mc) {
                const bfrag b = *(const bfrag*)&ew2[((size_t)(kb * tpm + g0 + tt) * 64 + lane) * 8];
#pragma unroll
                for (int rr = 0; rr < 4; ++rr)
                    acc[tt][rr] = __builtin_amdgcn_mfma_f32_16x16x32_bf16(a[rr], b, acc[tt][rr], 0, 0, 0);
            }
        }
    }

    bfrag bpre[TPW];
#pragma unroll 1
    for (int j = 0; j < nch; ++j) {
        const int cbase = 32 * j;
        if (cbase >= Mc) break;

        const bfrag bc = *(const bfrag*)&bfx[((size_t)j * 64 + lane) * 8];

        if (j > 0) {
            const int pr = (j - 1) & 1;
            bfrag a[4];
#pragma unroll
            for (int rr = 0; rr < 4; ++rr)
                a[rr] = *(const bfrag*)&res2[pr][(rr * 64 + lane) * 8];
#pragma unroll
            for (int tt = 0; tt < TPW; ++tt) {
                const int col0 = (g0 + tt) * 16;
                if (col0 >= cbase && col0 < Mc) {
#pragma unroll
                    for (int rr = 0; rr < 4; ++rr)
                        acc[tt][rr] = __builtin_amdgcn_mfma_f32_16x16x32_bf16(a[rr], bpre[tt], acc[tt][rr], 0, 0, 0);
                }
            }
        }
#pragma unroll
        for (int tt = 0; tt < TPW; ++tt) {
            const int col0 = (g0 + tt) * 16;
            if (col0 >= 32 * (j + 1) && col0 < Mc)
                bpre[tt] = *(const bfrag*)&ew2[((size_t)((16 + j) * tpm + g0 + tt) * 64 + lane) * 8];
        }

        const int ow = (2 * j) / TPW;
        if (w == ow) {
#pragma unroll
            for (int tt = 0; tt < TPW; ++tt) {
                if (g0 + tt == 2 * j) {
#pragma unroll
                    for (int rr = 0; rr < 4; ++rr)
                        *(ffrag*)&stage2[l15 * 68 + rr * 16 + 4 * q] = acc[tt][rr];
                }
            }
            const float* trij = tri_lds[j & 1];
            float reg[32];
#pragma unroll
            for (int c = 0; c < 16; ++c) reg[c] = stage2[c * 68 + lane];

            float4 tr[2][8];
#pragma unroll
            for (int u = 0; u < 4; ++u) tr[0][u] = *(const float4*)&trij[u * 4];

#pragma unroll
            for (int c = 0; c < 16; ++c) {
                const int cb = c & 1;
                if (c < 15) {
#pragma unroll
                    for (int u = (c + 2) >> 2; u < 4; ++u)
                        tr[cb ^ 1][u] = *(const float4*)&trij[(c + 1) * 32 + u * 4];
                }
                const float e  = fast_exp2(reg[c]);
                const float s  = fast_rcp(1.f + e);
                const float rs = s + bias_lds[cbase + c];
                reg[c] = rs;
#pragma unroll
                for (int k = c + 1; k < 16; ++k)
                    reg[k] = fmaf(rs, f4c(tr[cb][k >> 2], k & 3), reg[k]);
            }
            unsigned short* resb = res2[j & 1];
            const int rowA = (q * 64 + l15) * 8;
#pragma unroll
            for (int qA = 0; qA < 2; ++qA) {
                unsigned int u[4];
#pragma unroll
                for (int i = 0; i < 4; ++i)
                    u[i] = cvt_pk_bf16(reg[qA * 8 + 2 * i], reg[qA * 8 + 2 * i + 1]);
                *(uint4*)&resb[rowA + qA * 128] = *(uint4*)u;
            }
            bfrag aB[4];
#pragma unroll
            for (int rr = 0; rr < 4; ++rr)
                aB[rr] = *(const bfrag*)&resb[(rr * 64 + lane) * 8];
#pragma unroll
            for (int tt = 0; tt < TPW; ++tt) {
                if (g0 + tt == 2 * j + 1) {
#pragma unroll
                    for (int rr = 0; rr < 4; ++rr)
                        acc[tt][rr] = __builtin_amdgcn_mfma_f32_16x16x32_bf16(aB[rr], bc, acc[tt][rr], 0, 0, 0);
#pragma unroll
                    for (int rr = 0; rr < 4; ++rr)
                        *(ffrag*)&stage2[(16 + l15) * 68 + rr * 16 + 4 * q] = acc[tt][rr];
                }
            }
#pragma unroll
            for (int c = 16; c < 32; ++c) reg[c] = stage2[c * 68 + lane];
#pragma unroll
            for (int u = 4; u < 8; ++u) tr[0][u] = *(const float4*)&trij[16 * 32 + u * 4];

#pragma unroll
            for (int c = 16; c < 32; ++c) {
                const int cb = c & 1;
                if (c < 31) {
#pragma unroll
                    for (int u = (c + 2) >> 2; u < 8; ++u)
                        tr[cb ^ 1][u] = *(const float4*)&trij[(c + 1) * 32 + u * 4];
                }
                const float e  = fast_exp2(reg[c]);
                const float s  = fast_rcp(1.f + e);
                const float rs = s + bias_lds[cbase + c];
                reg[c] = rs;
#pragma unroll
                for (int k = c + 1; k < 32; ++k)
                    reg[k] = fmaf(rs, f4c(tr[cb][k >> 2], k & 3), reg[k]);
            }
#pragma unroll
            for (int qA = 2; qA < 4; ++qA) {
                unsigned int u[4];
#pragma unroll
                for (int i = 0; i < 4; ++i)
                    u[i] = cvt_pk_bf16(reg[qA * 8 + 2 * i], reg[qA * 8 + 2 * i + 1]);
                *(uint4*)&resb[rowA + qA * 128] = *(uint4*)u;
            }
#pragma unroll
            for (int c4 = 0; c4 < 8; ++c4) {
                const int oc0 = ocol_lds[cbase + c4 * 4];
                const int oc3 = ocol_lds[cbase + c4 * 4 + 3];
                if (oc0 >= 0 && oc3 == oc0 + 3 && (oc0 & 3) == 0) {
                    const float4 v = make_float4(reg[c4 * 4], reg[c4 * 4 + 1],
                                                 reg[c4 * 4 + 2], reg[c4 * 4 + 3]);
                    *(float4*)&out[(size_t)(r0 + lane) * OUT_DIM + oc0] = v;
                } else {
#pragma unroll
                    for (int c = c4 * 4; c < c4 * 4 + 4; ++c) {
                        const int oc = ocol_lds[cbase + c];
                        if (oc >= 0)
                            out[(size_t)(r0 + lane) * OUT_DIM + oc] = reg[c];
                    }
                }
            }
        } else if (w == ((ow + 2) & 3)) {
            const int jn = j + 1;
            if (jn < nch && 32 * jn < Mc) {
                const float4* src = (const float4*)(tri_g + (size_t)jn * 1024);
#pragma unroll
                for (int u = 0; u < 4; ++u)
                    *(float4*)&tri_lds[jn & 1][(lane + 64 * u) * 4] = src[lane + 64 * u];
            }
        }
        __syncthreads();
    }
}

// ============================================================
// Fallback (Mc > 1024 or tiny ws): round-1 monolithic fp32 kernel.
// ============================================================
__global__ __launch_bounds__(NT, 4)
void net_v1_kernel(const float* __restrict__ x,
                   const float* __restrict__ wsrc,
                   const int* __restrict__ conn,
                   const float* __restrict__ bias,
                   const int* __restrict__ exist,
                   const int* __restrict__ hdr,   // null = always run
                   float* __restrict__ out) {
    if (hdr && hdr[1] <= 1024) return;
    __shared__ float xs[16 * XPAD];
    __shared__ float res_s[2][16];
    float* bias_s  = xs;
    float* exist_s = xs + N_MID;
    const int t = threadIdx.x, rg = t & 3, cg = t >> 2;
    const int r0 = blockIdx.x * 16;
    const int c0 = cg * 20;
    {
        const float4* xg = (const float4*)(x + (size_t)r0 * IN_DIM);
        for (int idx = t; idx < 16 * IN_DIM / 4; idx += NT) {
            const int r = idx >> 7, jj = idx & 127;
            *(float4*)&xs[r * XPAD + jj * 4] = xg[idx];
        }
    }
    __syncthreads();
    float acc[4][20];
#pragma unroll
    for (int a = 0; a < 4; ++a)
#pragma unroll
        for (int k = 0; k < 20; ++k) acc[a][k] = 0.f;
    for (int j = 0; j < IN_DIM; ++j) {
        const size_t woff = (size_t)j * N_MID + c0;
        const float xv0 = xs[rg * XPAD + j];
        const float xv1 = xs[(rg + 4) * XPAD + j];
        const float xv2 = xs[(rg + 8) * XPAD + j];
        const float xv3 = xs[(rg + 12) * XPAD + j];
#pragma unroll
        for (int qq = 0; qq < 5; ++qq) {
            float4 w4 = *(const float4*)(wsrc + woff + qq * 4);
            const int4 c4 = *(const int4*)(conn + woff + qq * 4);
            w4.x *= (float)c4.x; w4.y *= (float)c4.y;
            w4.z *= (float)c4.z; w4.w *= (float)c4.w;
            const float wq[4] = {w4.x, w4.y, w4.z, w4.w};
#pragma unroll
            for (int u = 0; u < 4; ++u) {
                const int k = qq * 4 + u;
                acc[0][k] = fmaf(xv0, wq[u], acc[0][k]);
                acc[1][k] = fmaf(xv1, wq[u], acc[1][k]);
                acc[2][k] = fmaf(xv2, wq[u], acc[2][k]);
                acc[3][k] = fmaf(xv3, wq[u], acc[3][k]);
            }
        }
    }
    __syncthreads();
    for (int idx = t; idx < N_MID; idx += NT) {
        bias_s[idx]  = bias[idx];
        exist_s[idx] = (float)exist[idx];
    }
    __syncthreads();
    int p = 0;
    for (int bb = 0; bb < 64; ++bb) {
#pragma unroll
        for (int kk = 0; kk < 20; ++kk) {
            const int i = bb * 20 + kk;
            const float e = exist_s[i];
            if (e != 0.f) {
                if (cg == bb) {
                    const float bv = bias_s[i];
#pragma unroll
                    for (int a = 0; a < 4; ++a) {
                        const float v = acc[a][kk];
                        const float s = __fdividef(1.f, 1.f + __expf(-v));
                        const float res = (s + bv) * e;
                        res_s[p][rg + 4 * a] = res;
                        if (i >= N_MID - OUT_DIM)
                            out[(size_t)(r0 + rg + 4 * a) * OUT_DIM + (i - (N_MID - OUT_DIM))] = res;
                    }
                }
                __syncthreads();
                const float rv0 = res_s[p][rg];
                const float rv1 = res_s[p][rg + 4];
                const float rv2 = res_s[p][rg + 8];
                const float rv3 = res_s[p][rg + 12];
                const size_t woff = (size_t)(IN_DIM + i) * N_MID + c0;
                if (cg > bb) {
#pragma unroll
                    for (int qq = 0; qq < 5; ++qq) {
                        float4 w4 = *(const float4*)(wsrc + woff + qq * 4);
                        const int4 c4 = *(const int4*)(conn + woff + qq * 4);
                        w4.x *= (float)c4.x; w4.y *= (float)c4.y;
                        w4.z *= (float)c4.z; w4.w *= (float)c4.w;
                        const float wq[4] = {w4.x, w4.y, w4.z, w4.w};
#pragma unroll
                        for (int u = 0; u < 4; ++u) {
                            const int k = qq * 4 + u;
                            acc[0][k] = fmaf(rv0, wq[u], acc[0][k]);
                            acc[1][k] = fmaf(rv1, wq[u], acc[1][k]);
                            acc[2][k] = fmaf(rv2, wq[u], acc[2][k]);
                            acc[3][k] = fmaf(rv3, wq[u], acc[3][k]);
                        }
                    }
                } else if (cg == bb) {
#pragma unroll
                    for (int k = kk + 1; k < 20; ++k) {
                        float ww = wsrc[woff + k] * (float)conn[woff + k];
                        acc[0][k] = fmaf(rv0, ww, acc[0][k]);
                        acc[1][k] = fmaf(rv1, ww, acc[1][k]);
                        acc[2][k] = fmaf(rv2, ww, acc[2][k]);
                        acc[3][k] = fmaf(rv3, ww, acc[3][k]);
                    }
                }
                p ^= 1;
            }
        }
    }
}

extern "C" void kernel_launch(void* const* d_in, const int* in_sizes, int n_in,
                              void* d_out, int out_size, void* d_ws, size_t ws_size,
                              hipStream_t stream) {
    const float* x      = (const float*)d_in[0];
    const float* weight = (const float*)d_in[1];
    const float* bias   = (const float*)d_in[2];
    const int*   conn   = (const int*)d_in[3];
    const int*   exist  = (const int*)d_in[4];
    float*       out    = (float*)d_out;

    if (ws_size >= WS_NEED) {
        char* ws = (char*)d_ws;
        unsigned short* ew2  = (unsigned short*)ws;
        float*          tri  = (float*)(ws + TRI_OFF);
        int*            hdr  = (int*)(ws + HDR_OFF);
        int*            cmap = (int*)(ws + CMAP_OFF);
        int*            ocolp= (int*)(ws + OCOL_OFF);
        float*          bsc  = (float*)(ws + BIASC_OFF);
        unsigned short* bfx  = (unsigned short*)(ws + BFX_OFF);

        build_maps_kernel<<<1, 64, 0, stream>>>(exist, bias, hdr, cmap, ocolp, bsc);
        gather_all_kernel<<<904, NT, 0, stream>>>(weight, conn, hdr, cmap, ew2, tri, bfx);
        net10_kernel<12><<<BATCH / 64, 256, 0, stream>>>(x, ew2, tri, hdr, ocolp, bsc, bfx, out);
        net7_kernel<16><<<BATCH / 64, 256, 0, stream>>>(x, ew2, tri, hdr, ocolp, bsc, bfx, out);
        net_v1_kernel<<<BATCH / 16, NT, 0, stream>>>(x, weight, conn, bias, exist, hdr, out);
    } else {
        net_v1_kernel<<<BATCH / 16, NT, 0, stream>>>(x, weight, conn, bias, exist, nullptr, out);
    }
}

// Round 11
// 261.615 us; speedup vs baseline: 2.3536x; 1.2950x over previous
//
#include <hip/hip_runtime.h>

#define IN_DIM   512
#define OUT_DIM  256
#define N_MID    1280
#define BATCH    16384
#define NT       256
#define XPAD     520      // fallback kernel x stride

// History: net7 (4-wave lockstep, 1 barrier/chunk) = 185us best (R15).
// R15 ablation: scaffolding ~160us, resolve ~25us -> latency-stall dominated.
// Structural alternatives ALL lost: R16 2-blocks/CU 207us; R18 running-apply
//   528us (spill + conflicts); R19 panel form 252us (more mem ops on the
//   1-wave/SIMD latency chain). Conclusion: net7's minimal per-chunk memory-op
//   count beats "better" structures with more traffic; keep net7.
// R20 (this round): restore R12/R15 best-known config exactly, plus:
//   (1) DEFERRED out-stores: owner buffers chunk outputs in pend[32] regs,
//       issues stores at next owner-section start / after loop -> the
//       pre-barrier vmcnt(0) drain no longer waits on fresh stores.
//   (2) bc (bfx) load moved inside the owner branch (was loaded by all 4).

// ---- workspace layout (max geometry: ksteps=48, tpm=64, nch=32) ----
#define EW2_ELEMS ((size_t)48 * 64 * 64 * 8)               // bf16 elems
#define EW2_BYTES (EW2_ELEMS * 2)                          // 3,145,728
#define TRI_OFF   EW2_BYTES
#define TRI_BYTES ((size_t)32 * 1024 * 4)                  // 131,072
#define HDR_OFF   (TRI_OFF + TRI_BYTES)
#define CMAP_OFF  (HDR_OFF + 32)
#define OCOL_OFF  (CMAP_OFF + N_MID * 4)
#define BIASC_OFF (OCOL_OFF + N_MID * 4)
#define BFX_OFF   (BIASC_OFF + N_MID * 4)
#define BFX_BYTES ((size_t)32 * 64 * 8 * 2)                // 32,768
#define WS_NEED   (BFX_OFF + BFX_BYTES)

#define NEG_LOG2E (-1.44269504088896340736f)

typedef __attribute__((ext_vector_type(8))) short  bfrag;
typedef __attribute__((ext_vector_type(4))) float  ffrag;

__device__ __forceinline__ unsigned short f2bf(float f) {
    unsigned int u = __float_as_uint(f);
    u += 0x7FFFu + ((u >> 16) & 1u);       // RNE
    return (unsigned short)(u >> 16);
}

// raw HW exp2 (no OCML subnormal fixup -- R11 lesson)
__device__ __forceinline__ float fast_exp2(float x) {
#if __has_builtin(__builtin_amdgcn_exp2f)
    return __builtin_amdgcn_exp2f(x);
#else
    float r;
    asm("v_exp_f32 %0, %1" : "=v"(r) : "v"(x));
    return r;
#endif
}

// raw HW rcp (single instr)
__device__ __forceinline__ float fast_rcp(float x) {
#if __has_builtin(__builtin_amdgcn_rcpf)
    return __builtin_amdgcn_rcpf(x);
#else
    float r;
    asm("v_rcp_f32 %0, %1" : "=v"(r) : "v"(x));
    return r;
#endif
}

// packed f32x2 -> bf16x2 (RNE)
__device__ __forceinline__ unsigned int cvt_pk_bf16(float lo, float hi) {
    unsigned int r;
    asm("v_cvt_pk_bf16_f32 %0, %1, %2" : "=v"(r) : "v"(lo), "v"(hi));
    return r;
}

// ============================================================
// Setup A: compact existing columns (1 wave).
// hdr = {Mc, Mpad, unused, nch=Mpad/32, tpm=Mpad/16}
// ============================================================
__global__ void build_maps_kernel(const int* __restrict__ exist,
                                  const float* __restrict__ bias,
                                  int* __restrict__ hdr,
                                  int* __restrict__ cmap,
                                  int* __restrict__ ocol,
                                  float* __restrict__ biasc) {
    const int lane = threadIdx.x;   // 64
    int base = 0;
    for (int r = 0; r < N_MID / 64; ++r) {
        const int i = r * 64 + lane;
        const int e = exist[i];
        const unsigned long long m  = __ballot(e != 0);
        const unsigned long long lt = (lane == 0) ? 0ull : (~0ull >> (64 - lane));
        const int pos = base + __popcll(m & lt);
        if (e) {
            cmap[pos]  = i;
            ocol[pos]  = (i >= N_MID - OUT_DIM) ? (i - (N_MID - OUT_DIM)) : -1;
            biasc[pos] = bias[i];
        }
        base += __popcll(m);
    }
    for (int idx = base + lane; idx < N_MID; idx += 64) {
        cmap[idx] = 0; ocol[idx] = -1; biasc[idx] = 0.f;
    }
    if (lane == 0) {
        const int Mc = base;
        int Mpad;
        if (Mc <= 768) Mpad = 768;
        else if (Mc <= 1024) Mpad = 1024;
        else Mpad = (Mc + 127) & ~127;     // v1 fallback territory
        hdr[0] = Mc; hdr[1] = Mpad; hdr[2] = 0;
        hdr[3] = Mpad / 32; hdr[4] = Mpad / 16;
    }
}

// ============================================================
// Setup B (merged, ONE dispatch): all weights PRE-SCALED by -log2e.
//  blocks [0,768):   ew2 gather -> bf16 MFMA B-fragment-major.
//  blocks [768,896): tri = in-chunk triangle, fp32, scaled.
//  blocks [896,904): bfx = in-chunk lower->upper cross block, bf16 B-frags,
//    scaled, zero for k>=16.
// ============================================================
__global__ __launch_bounds__(NT)
void gather_all_kernel(const float* __restrict__ w, const int* __restrict__ conn,
                       const int* __restrict__ hdr, const int* __restrict__ cmap,
                       unsigned short* __restrict__ ew2, float* __restrict__ tri,
                       unsigned short* __restrict__ bfx) {
    const int Mc = hdr[0], nch = hdr[3], tpm = hdr[4];
    const int bx = blockIdx.x;
    if (bx < 768) {
        if (tpm > 64) return;                      // v1 fallback case
        const int tid  = bx * NT + threadIdx.x;
        const int lane = tid & 63;
        const int gl   = tid >> 6;
        const int gt   = gl % tpm;
        const int kstep = gl / tpm;
        if (kstep >= 16 + nch) return;
        const int c  = gt * 16 + (lane & 15);
        const int k0 = kstep * 32 + ((lane >> 4) << 3);
        unsigned short v[8];
#pragma unroll
        for (int jj = 0; jj < 8; ++jj) {
            const int s = k0 + jj;
            float val = 0.f;
            if (c < Mc) {
                const int cc = cmap[c];
                if (s < IN_DIM) {
                    const size_t o = (size_t)s * N_MID + cc;
                    val = w[o] * (float)conn[o] * NEG_LOG2E;
                } else {
                    const int s2 = s - IN_DIM;
                    if (s2 < Mc && s2 < c && (s2 >> 5) != (c >> 5)) {
                        const size_t o = (size_t)(IN_DIM + cmap[s2]) * N_MID + cc;
                        val = w[o] * (float)conn[o] * NEG_LOG2E;
                    }
                }
            }
            v[jj] = f2bf(val);
        }
        *(uint4*)&ew2[((size_t)(kstep * tpm + gt) * 64 + lane) * 8] = *(uint4*)v;
    } else if (bx < 896) {
        if (tpm > 64) return;
        const int idx = (bx - 768) * NT + threadIdx.x;   // < 32*1024
        const int j  = idx >> 10;
        if (j >= nch) return;
        const int sl = (idx >> 5) & 31;
        const int cl = idx & 31;
        const int s = j * 32 + sl, c = j * 32 + cl;
        float v = 0.f;
        if (sl < cl && c < Mc) {
            const size_t o = (size_t)(IN_DIM + cmap[s]) * N_MID + cmap[c];
            v = w[o] * (float)conn[o] * NEG_LOG2E;
        }
        tri[idx] = v;
    } else {
        if (tpm > 64) return;
        const int j = (bx - 896) * 4 + (threadIdx.x >> 6);
        if (j >= nch || j >= 32) return;
        const int lane = threadIdx.x & 63;
        const int cl = lane & 15, qq = lane >> 4;
        const int cg = 32 * j + 16 + cl;
        unsigned short v[8];
#pragma unroll
        for (int jj = 0; jj < 8; ++jj) {
            const int k = qq * 8 + jj;
            float val = 0.f;
            if (k < 16 && cg < Mc) {
                const size_t o = (size_t)(IN_DIM + cmap[32 * j + k]) * N_MID + cmap[cg];
                val = w[o] * (float)conn[o] * NEG_LOG2E;
            }
            v[jj] = f2bf(val);
        }
        *(uint4*)&bfx[((size_t)j * 64 + lane) * 8] = *(uint4*)v;
    }
}

// helper: static component select from float4 (constant-folded post-unroll)
__device__ __forceinline__ float f4c(const float4& v, int k) {
    return (k == 0) ? v.x : (k == 1) ? v.y : (k == 2) ? v.z : v.w;
}

// ============================================================
// Main kernel (net7, R15-verified 185us): 256 blocks x 256 threads (4 waves),
// 64 rows/block. One barrier per chunk. 16+16 split resolver + MFMA bridge.
// exp2 domain (setup prescale); chain: exp2 -> add1 -> rcp -> add bias -> fma.
// R20: deferred out-stores (pend regs) + bc load owner-only.
// ============================================================
template <int TPW>
__global__ __launch_bounds__(256)
__attribute__((amdgpu_waves_per_eu(1, 1)))
void net7_kernel(const float* __restrict__ x,
                 const unsigned short* __restrict__ ew2,
                 const float* __restrict__ tri_g,
                 const int* __restrict__ hdr,
                 const int* __restrict__ ocol,
                 const float* __restrict__ biasc,
                 const unsigned short* __restrict__ bfx,
                 float* __restrict__ out) {
    if (hdr[1] != TPW * 64) return;
    const int Mc  = hdr[0];
    const int tpm = TPW * 4;                   // Mpad/16
    const int nch = TPW * 2;                   // Mpad/32

    __shared__ __align__(16) unsigned short xa[4096 * 8];      // 65,536 B
    __shared__ __align__(16) float stage2[32 * 68];            //  8,704 B
    __shared__ __align__(16) unsigned short res2[2][2048];     //  8,192 B
    __shared__ __align__(16) float tri_lds[2][1024];           //  8,192 B
    __shared__ float bias_lds[1024];                           //  4,096 B
    __shared__ int   ocol_lds[1024];                           //  4,096 B

    const int t = threadIdx.x, lane = t & 63, w = t >> 6;  // w in 0..3
    const int l15 = lane & 15, q = lane >> 4;
    const int r0 = blockIdx.x * 64;
    const int g0 = w * TPW;

    for (int i = t; i < TPW * 64; i += 256) {
        bias_lds[i] = biasc[i];
        ocol_lds[i] = ocol[i];
    }
    {
        uint4 z; z.x = 0u; z.y = 0u; z.z = 0u; z.w = 0u;
        uint4* r2 = (uint4*)res2;
        for (int i = t; i < 512; i += 256) r2[i] = z;
    }
    if (w == 3) {
        const float4* src = (const float4*)tri_g;
#pragma unroll
        for (int u = 0; u < 4; ++u)
            *(float4*)&tri_lds[0][(lane + 64 * u) * 4] = src[lane + 64 * u];
    }
    for (int i = t; i < 4096; i += 256) {
        const int lane2 = i & 63, rrkb = i >> 6;
        const int rr = rrkb & 3, kb = rrkb >> 2;
        const int qq = lane2 >> 4, ll = lane2 & 15;
        const int row = rr * 16 + ll;
        const int k0 = kb * 32 + qq * 8;
        const float4 f0 = *(const float4*)&x[(size_t)(r0 + row) * IN_DIM + k0];
        const float4 f1 = *(const float4*)&x[(size_t)(r0 + row) * IN_DIM + k0 + 4];
        unsigned int uu[4] = {cvt_pk_bf16(f0.x, f0.y), cvt_pk_bf16(f0.z, f0.w),
                              cvt_pk_bf16(f1.x, f1.y), cvt_pk_bf16(f1.z, f1.w)};
        *(uint4*)&xa[(size_t)i * 8] = *(uint4*)uu;
    }
    __syncthreads();

    ffrag acc[TPW][4];
#pragma unroll
    for (int tt = 0; tt < TPW; ++tt)
#pragma unroll
        for (int rr = 0; rr < 4; ++rr) acc[tt][rr] = (ffrag)0.f;

#pragma unroll 1
    for (int kb = 0; kb < 16; ++kb) {
        bfrag a[4];
#pragma unroll
        for (int rr = 0; rr < 4; ++rr)
            a[rr] = *(const bfrag*)&xa[((kb * 4 + rr) * 64 + lane) * 8];
#pragma unroll
        for (int tt = 0; tt < TPW; ++tt) {
            if ((g0 + tt) * 16 < Mc) {
                const bfrag b = *(const bfrag*)&ew2[((size_t)(kb * tpm + g0 + tt) * 64 + lane) * 8];
#pragma unroll
                for (int rr = 0; rr < 4; ++rr)
                    acc[tt][rr] = __builtin_amdgcn_mfma_f32_16x16x32_bf16(a[rr], b, acc[tt][rr], 0, 0, 0);
            }
        }
    }

    // deferred out-store state (R20)
    float pend[32];
    int pcbase = -1;

    bfrag bpre[TPW];
#pragma unroll 1
    for (int j = 0; j < nch; ++j) {
        const int cbase = 32 * j;
        if (cbase >= Mc) break;

        if (j > 0) {
            const int pr = (j - 1) & 1;
            bfrag a[4];
#pragma unroll
            for (int rr = 0; rr < 4; ++rr)
                a[rr] = *(const bfrag*)&res2[pr][(rr * 64 + lane) * 8];
#pragma unroll
            for (int tt = 0; tt < TPW; ++tt) {
                const int col0 = (g0 + tt) * 16;
                if (col0 >= cbase && col0 < Mc) {
#pragma unroll
                    for (int rr = 0; rr < 4; ++rr)
                        acc[tt][rr] = __builtin_amdgcn_mfma_f32_16x16x32_bf16(a[rr], bpre[tt], acc[tt][rr], 0, 0, 0);
                }
            }
        }
#pragma unroll
        for (int tt = 0; tt < TPW; ++tt) {
            const int col0 = (g0 + tt) * 16;
            if (col0 >= 32 * (j + 1) && col0 < Mc)
                bpre[tt] = *(const bfrag*)&ew2[((size_t)((16 + j) * tpm + g0 + tt) * 64 + lane) * 8];
        }

        const int ow = (2 * j) / TPW;
        if (w == ow) {
            // ---- flush deferred stores from previous owned chunk (R20):
            //      issued here, they retire during this chunk's resolve ----
            if (pcbase >= 0) {
#pragma unroll
                for (int c4 = 0; c4 < 8; ++c4) {
                    const int oc0 = ocol_lds[pcbase + c4 * 4];
                    const int oc3 = ocol_lds[pcbase + c4 * 4 + 3];
                    if (oc0 >= 0 && oc3 == oc0 + 3 && (oc0 & 3) == 0) {
                        const float4 v = make_float4(pend[c4 * 4], pend[c4 * 4 + 1],
                                                     pend[c4 * 4 + 2], pend[c4 * 4 + 3]);
                        *(float4*)&out[(size_t)(r0 + lane) * OUT_DIM + oc0] = v;
                    } else {
#pragma unroll
                        for (int c = c4 * 4; c < c4 * 4 + 4; ++c) {
                            const int oc = ocol_lds[pcbase + c];
                            if (oc >= 0)
                                out[(size_t)(r0 + lane) * OUT_DIM + oc] = pend[c];
                        }
                    }
                }
                pcbase = -1;
            }
            const bfrag bc = *(const bfrag*)&bfx[((size_t)j * 64 + lane) * 8];  // owner-only (R20)
#pragma unroll
            for (int tt = 0; tt < TPW; ++tt) {
                if (g0 + tt == 2 * j) {
#pragma unroll
                    for (int rr = 0; rr < 4; ++rr)
                        *(ffrag*)&stage2[l15 * 68 + rr * 16 + 4 * q] = acc[tt][rr];
                }
            }
            const float* trij = tri_lds[j & 1];
            float reg[32];
#pragma unroll
            for (int c = 0; c < 16; ++c) reg[c] = stage2[c * 68 + lane];

            float4 tr[2][8];
#pragma unroll
            for (int u = 0; u < 4; ++u) tr[0][u] = *(const float4*)&trij[u * 4];

#pragma unroll
            for (int c = 0; c < 16; ++c) {
                const int cb = c & 1;
                if (c < 15) {
#pragma unroll
                    for (int u = (c + 2) >> 2; u < 4; ++u)
                        tr[cb ^ 1][u] = *(const float4*)&trij[(c + 1) * 32 + u * 4];
                }
                const float e  = fast_exp2(reg[c]);
                const float s  = fast_rcp(1.f + e);
                const float rs = s + bias_lds[cbase + c];
                reg[c] = rs;
#pragma unroll
                for (int k = c + 1; k < 16; ++k)
                    reg[k] = fmaf(rs, f4c(tr[cb][k >> 2], k & 3), reg[k]);
            }
            unsigned short* resb = res2[j & 1];
            const int rowA = (q * 64 + l15) * 8;
#pragma unroll
            for (int qA = 0; qA < 2; ++qA) {
                unsigned int u[4];
#pragma unroll
                for (int i = 0; i < 4; ++i)
                    u[i] = cvt_pk_bf16(reg[qA * 8 + 2 * i], reg[qA * 8 + 2 * i + 1]);
                *(uint4*)&resb[rowA + qA * 128] = *(uint4*)u;
            }
            bfrag aB[4];
#pragma unroll
            for (int rr = 0; rr < 4; ++rr)
                aB[rr] = *(const bfrag*)&resb[(rr * 64 + lane) * 8];
#pragma unroll
            for (int tt = 0; tt < TPW; ++tt) {
                if (g0 + tt == 2 * j + 1) {
#pragma unroll
                    for (int rr = 0; rr < 4; ++rr)
                        acc[tt][rr] = __builtin_amdgcn_mfma_f32_16x16x32_bf16(aB[rr], bc, acc[tt][rr], 0, 0, 0);
#pragma unroll
                    for (int rr = 0; rr < 4; ++rr)
                        *(ffrag*)&stage2[(16 + l15) * 68 + rr * 16 + 4 * q] = acc[tt][rr];
                }
            }
#pragma unroll
            for (int c = 16; c < 32; ++c) reg[c] = stage2[c * 68 + lane];
#pragma unroll
            for (int u = 4; u < 8; ++u) tr[0][u] = *(const float4*)&trij[16 * 32 + u * 4];

#pragma unroll
            for (int c = 16; c < 32; ++c) {
                const int cb = c & 1;
                if (c < 31) {
#pragma unroll
                    for (int u = (c + 2) >> 2; u < 8; ++u)
                        tr[cb ^ 1][u] = *(const float4*)&trij[(c + 1) * 32 + u * 4];
                }
                const float e  = fast_exp2(reg[c]);
                const float s  = fast_rcp(1.f + e);
                const float rs = s + bias_lds[cbase + c];
                reg[c] = rs;
#pragma unroll
                for (int k = c + 1; k < 32; ++k)
                    reg[k] = fmaf(rs, f4c(tr[cb][k >> 2], k & 3), reg[k]);
            }
#pragma unroll
            for (int qA = 2; qA < 4; ++qA) {
                unsigned int u[4];
#pragma unroll
                for (int i = 0; i < 4; ++i)
                    u[i] = cvt_pk_bf16(reg[qA * 8 + 2 * i], reg[qA * 8 + 2 * i + 1]);
                *(uint4*)&resb[rowA + qA * 128] = *(uint4*)u;
            }
            // ---- defer out stores: buffer in regs (R20). Chunk has outputs
            //      iff its last col index >= Mc - OUT_DIM (uniform). ----
            if (cbase + 31 >= Mc - OUT_DIM) {
#pragma unroll
                for (int c = 0; c < 32; ++c) pend[c] = reg[c];
                pcbase = cbase;
            }
        } else if (w == ((ow + 2) & 3)) {
            const int jn = j + 1;
            if (jn < nch && 32 * jn < Mc) {
                const float4* src = (const float4*)(tri_g + (size_t)jn * 1024);
#pragma unroll
                for (int u = 0; u < 4; ++u)
                    *(float4*)&tri_lds[jn & 1][(lane + 64 * u) * 4] = src[lane + 64 * u];
            }
        }
        __syncthreads();
    }
    // ---- final flush of deferred stores ----
    if (pcbase >= 0) {
#pragma unroll
        for (int c4 = 0; c4 < 8; ++c4) {
            const int oc0 = ocol_lds[pcbase + c4 * 4];
            const int oc3 = ocol_lds[pcbase + c4 * 4 + 3];
            if (oc0 >= 0 && oc3 == oc0 + 3 && (oc0 & 3) == 0) {
                const float4 v = make_float4(pend[c4 * 4], pend[c4 * 4 + 1],
                                             pend[c4 * 4 + 2], pend[c4 * 4 + 3]);
                *(float4*)&out[(size_t)(r0 + lane) * OUT_DIM + oc0] = v;
            } else {
#pragma unroll
                for (int c = c4 * 4; c < c4 * 4 + 4; ++c) {
                    const int oc = ocol_lds[pcbase + c];
                    if (oc >= 0)
                        out[(size_t)(r0 + lane) * OUT_DIM + oc] = pend[c];
                }
            }
        }
    }
}

// ============================================================
// Fallback (Mc > 1024 or tiny ws): round-1 monolithic fp32 kernel.
// ============================================================
__global__ __launch_bounds__(NT, 4)
void net_v1_kernel(const float* __restrict__ x,
                   const float* __restrict__ wsrc,
                   const int* __restrict__ conn,
                   const float* __restrict__ bias,
                   const int* __restrict__ exist,
                   const int* __restrict__ hdr,   // null = always run
                   float* __restrict__ out) {
    if (hdr && hdr[1] <= 1024) return;
    __shared__ float xs[16 * XPAD];
    __shared__ float res_s[2][16];
    float* bias_s  = xs;
    float* exist_s = xs + N_MID;
    const int t = threadIdx.x, rg = t & 3, cg = t >> 2;
    const int r0 = blockIdx.x * 16;
    const int c0 = cg * 20;
    {
        const float4* xg = (const float4*)(x + (size_t)r0 * IN_DIM);
        for (int idx = t; idx < 16 * IN_DIM / 4; idx += NT) {
            const int r = idx >> 7, jj = idx & 127;
            *(float4*)&xs[r * XPAD + jj * 4] = xg[idx];
        }
    }
    __syncthreads();
    float acc[4][20];
#pragma unroll
    for (int a = 0; a < 4; ++a)
#pragma unroll
        for (int k = 0; k < 20; ++k) acc[a][k] = 0.f;
    for (int j = 0; j < IN_DIM; ++j) {
        const size_t woff = (size_t)j * N_MID + c0;
        const float xv0 = xs[rg * XPAD + j];
        const float xv1 = xs[(rg + 4) * XPAD + j];
        const float xv2 = xs[(rg + 8) * XPAD + j];
        const float xv3 = xs[(rg + 12) * XPAD + j];
#pragma unroll
        for (int qq = 0; qq < 5; ++qq) {
            float4 w4 = *(const float4*)(wsrc + woff + qq * 4);
            const int4 c4 = *(const int4*)(conn + woff + qq * 4);
            w4.x *= (float)c4.x; w4.y *= (float)c4.y;
            w4.z *= (float)c4.z; w4.w *= (float)c4.w;
            const float wq[4] = {w4.x, w4.y, w4.z, w4.w};
#pragma unroll
            for (int u = 0; u < 4; ++u) {
                const int k = qq * 4 + u;
                acc[0][k] = fmaf(xv0, wq[u], acc[0][k]);
                acc[1][k] = fmaf(xv1, wq[u], acc[1][k]);
                acc[2][k] = fmaf(xv2, wq[u], acc[2][k]);
                acc[3][k] = fmaf(xv3, wq[u], acc[3][k]);
            }
        }
    }
    __syncthreads();
    for (int idx = t; idx < N_MID; idx += NT) {
        bias_s[idx]  = bias[idx];
        exist_s[idx] = (float)exist[idx];
    }
    __syncthreads();
    int p = 0;
    for (int bb = 0; bb < 64; ++bb) {
#pragma unroll
        for (int kk = 0; kk < 20; ++kk) {
            const int i = bb * 20 + kk;
            const float e = exist_s[i];
            if (e != 0.f) {
                if (cg == bb) {
                    const float bv = bias_s[i];
#pragma unroll
                    for (int a = 0; a < 4; ++a) {
                        const float v = acc[a][kk];
                        const float s = __fdividef(1.f, 1.f + __expf(-v));
                        const float res = (s + bv) * e;
                        res_s[p][rg + 4 * a] = res;
                        if (i >= N_MID - OUT_DIM)
                            out[(size_t)(r0 + rg + 4 * a) * OUT_DIM + (i - (N_MID - OUT_DIM))] = res;
                    }
                }
                __syncthreads();
                const float rv0 = res_s[p][rg];
                const float rv1 = res_s[p][rg + 4];
                const float rv2 = res_s[p][rg + 8];
                const float rv3 = res_s[p][rg + 12];
                const size_t woff = (size_t)(IN_DIM + i) * N_MID + c0;
                if (cg > bb) {
#pragma unroll
                    for (int qq = 0; qq < 5; ++qq) {
                        float4 w4 = *(const float4*)(wsrc + woff + qq * 4);
                        const int4 c4 = *(const int4*)(conn + woff + qq * 4);
                        w4.x *= (float)c4.x; w4.y *= (float)c4.y;
                        w4.z *= (float)c4.z; w4.w *= (float)c4.w;
                        const float wq[4] = {w4.x, w4.y, w4.z, w4.w};
#pragma unroll
                        for (int u = 0; u < 4; ++u) {
                            const int k = qq * 4 + u;
                            acc[0][k] = fmaf(rv0, wq[u], acc[0][k]);
                            acc[1][k] = fmaf(rv1, wq[u], acc[1][k]);
                            acc[2][k] = fmaf(rv2, wq[u], acc[2][k]);
                            acc[3][k] = fmaf(rv3, wq[u], acc[3][k]);
                        }
                    }
                } else if (cg == bb) {
#pragma unroll
                    for (int k = kk + 1; k < 20; ++k) {
                        float ww = wsrc[woff + k] * (float)conn[woff + k];
                        acc[0][k] = fmaf(rv0, ww, acc[0][k]);
                        acc[1][k] = fmaf(rv1, ww, acc[1][k]);
                        acc[2][k] = fmaf(rv2, ww, acc[2][k]);
                        acc[3][k] = fmaf(rv3, ww, acc[3][k]);
                    }
                }
                p ^= 1;
            }
        }
    }
}

extern "C" void kernel_launch(void* const* d_in, const int* in_sizes, int n_in,
                              void* d_out, int out_size, void* d_ws, size_t ws_size,
                              hipStream_t stream) {
    const float* x      = (const float*)d_in[0];
    const float* weight = (const float*)d_in[1];
    const float* bias   = (const float*)d_in[2];
    const int*   conn   = (const int*)d_in[3];
    const int*   exist  = (const int*)d_in[4];
    float*       out    = (float*)d_out;

    if (ws_size >= WS_NEED) {
        char* ws = (char*)d_ws;
        unsigned short* ew2  = (unsigned short*)ws;
        float*          tri  = (float*)(ws + TRI_OFF);
        int*            hdr  = (int*)(ws + HDR_OFF);
        int*            cmap = (int*)(ws + CMAP_OFF);
        int*            ocolp= (int*)(ws + OCOL_OFF);
        float*          bsc  = (float*)(ws + BIASC_OFF);
        unsigned short* bfx  = (unsigned short*)(ws + BFX_OFF);

        build_maps_kernel<<<1, 64, 0, stream>>>(exist, bias, hdr, cmap, ocolp, bsc);
        gather_all_kernel<<<904, NT, 0, stream>>>(weight, conn, hdr, cmap, ew2, tri, bfx);
        net7_kernel<12><<<BATCH / 64, 256, 0, stream>>>(x, ew2, tri, hdr, ocolp, bsc, bfx, out);
        net7_kernel<16><<<BATCH / 64, 256, 0, stream>>>(x, ew2, tri, hdr, ocolp, bsc, bfx, out);
        net_v1_kernel<<<BATCH / 16, NT, 0, stream>>>(x, weight, conn, bias, exist, hdr, out);
    } else {
        net_v1_kernel<<<BATCH / 16, NT, 0, stream>>>(x, weight, conn, bias, exist, nullptr, out);
    }
}